// Round 2
// baseline (190.214 us; speedup 1.0000x reference)
//
#include <hip/hip_runtime.h>

typedef __bf16 bf16;
typedef __bf16 bf16x8 __attribute__((ext_vector_type(8)));
typedef __bf16 bf16x4 __attribute__((ext_vector_type(4)));
typedef float f32x4 __attribute__((ext_vector_type(4)));

#define MFMA16(a, b, c) __builtin_amdgcn_mfma_f32_16x16x32_bf16(a, b, c, 0, 0, 0)

// ---------------------------------------------------------------------------
// f32 -> bf16 bulk convert (n divisible by 4).
// ---------------------------------------------------------------------------
__global__ __launch_bounds__(256) void f32_to_bf16_kernel(const float* __restrict__ in,
                                                          bf16* __restrict__ out, int n) {
    int i = (blockIdx.x * 256 + threadIdx.x) * 4;
    if (i < n) {
        float4 v = *(const float4*)&in[i];
        bf16x4 o = {(bf16)v.x, (bf16)v.y, (bf16)v.z, (bf16)v.w};
        *(bf16x4*)&out[i] = o;
    }
}

// ---------------------------------------------------------------------------
// f32 [R][C] -> bf16 [C][R] transpose, 32x32 LDS tiles.
// ---------------------------------------------------------------------------
__global__ __launch_bounds__(256) void transpose_f2b(const float* __restrict__ in,
                                                     bf16* __restrict__ out,
                                                     int R, int C) {
    __shared__ float tile[32][33];
    int tx = threadIdx.x & 31, ty = threadIdx.x >> 5;
    int c0 = blockIdx.x * 32, r0 = blockIdx.y * 32;
#pragma unroll
    for (int i = ty; i < 32; i += 8)
        tile[i][tx] = in[(size_t)(r0 + i) * C + c0 + tx];
    __syncthreads();
#pragma unroll
    for (int i = ty; i < 32; i += 8)
        out[(size_t)(c0 + i) * R + r0 + tx] = (bf16)tile[tx][i];
}

// ---------------------------------------------------------------------------
// V slice of qkv (bf16) -> vt[bh][64][2048]  (vt[bh][d][n] = V[b][n][h][d])
// ---------------------------------------------------------------------------
__global__ __launch_bounds__(256) void transpose_v_kernel(const bf16* __restrict__ qkv,
                                                          bf16* __restrict__ vt) {
    __shared__ bf16 tile[32][33];
    int tx = threadIdx.x & 31, ty = threadIdx.x >> 5;
    int bh = blockIdx.z, b = bh >> 3, h = bh & 7;
    int n0 = blockIdx.x * 32, d0 = blockIdx.y * 32;
#pragma unroll
    for (int i = ty; i < 32; i += 8)
        tile[i][tx] = qkv[(size_t)(b * 2048 + n0 + i) * 1536 + 1024 + h * 64 + d0 + tx];
    __syncthreads();
#pragma unroll
    for (int i = ty; i < 32; i += 8)
        vt[(size_t)(bh * 64 + d0 + i) * 2048 + n0 + tx] = tile[tx][i];
}

// ---------------------------------------------------------------------------
// C[M][N] = A[M][K] @ Bt[N][K]^T (+f32 bias), bf16 in, OutT out, fp32 acc.
// 128x128 tile, BK=64, 4 waves in 2x2, each wave 64x64 (4x4 of 16x16 MFMA).
// LDS stride 72 (pad +8) -> conflict-free ds_read_b128 fragments.
// ---------------------------------------------------------------------------
template <int ADD_BIAS, typename OutT>
__global__ __launch_bounds__(256) void gemm_bt_kernel(const bf16* __restrict__ A,
                                                      const bf16* __restrict__ Bt,
                                                      const float* __restrict__ bias,
                                                      OutT* __restrict__ C,
                                                      int M, int N, int K) {
    const int LDT = 72;
    __shared__ bf16 As[128 * LDT];
    __shared__ bf16 Bs[128 * LDT];
    int t = threadIdx.x;
    int lane = t & 63, w = t >> 6;
    int wr = w >> 1, wc = w & 1;
    int quad = lane >> 4, r16 = lane & 15;
    int m0 = blockIdx.y * 128, n0 = blockIdx.x * 128;

    const f32x4 fzero = {0.f, 0.f, 0.f, 0.f};
    f32x4 acc[4][4];
#pragma unroll
    for (int i = 0; i < 4; ++i)
#pragma unroll
        for (int j = 0; j < 4; ++j) acc[i][j] = fzero;

    int sr = t >> 3;         // 0..31
    int sc = (t & 7) * 8;    // 0..56

    for (int k0 = 0; k0 < K; k0 += 64) {
        __syncthreads();
#pragma unroll
        for (int p = 0; p < 4; ++p) {
            int r = p * 32 + sr;
            *(bf16x8*)&As[r * LDT + sc] = *(const bf16x8*)&A[(size_t)(m0 + r) * K + k0 + sc];
            *(bf16x8*)&Bs[r * LDT + sc] = *(const bf16x8*)&Bt[(size_t)(n0 + r) * K + k0 + sc];
        }
        __syncthreads();
#pragma unroll
        for (int ks = 0; ks < 2; ++ks) {
            bf16x8 af[4], bfr[4];
#pragma unroll
            for (int mt = 0; mt < 4; ++mt)
                af[mt] = *(const bf16x8*)&As[(wr * 64 + mt * 16 + r16) * LDT + ks * 32 + quad * 8];
#pragma unroll
            for (int nt = 0; nt < 4; ++nt)
                bfr[nt] = *(const bf16x8*)&Bs[(wc * 64 + nt * 16 + r16) * LDT + ks * 32 + quad * 8];
#pragma unroll
            for (int mt = 0; mt < 4; ++mt)
#pragma unroll
                for (int nt = 0; nt < 4; ++nt)
                    acc[mt][nt] = MFMA16(af[mt], bfr[nt], acc[mt][nt]);
        }
    }
    // C/D layout: col = lane&15 (n), row = quad*4+reg (m)  [m89/m91 verified]
#pragma unroll
    for (int mt = 0; mt < 4; ++mt)
#pragma unroll
        for (int nt = 0; nt < 4; ++nt)
#pragma unroll
            for (int r = 0; r < 4; ++r) {
                int row = m0 + wr * 64 + mt * 16 + quad * 4 + r;
                int col = n0 + wc * 64 + nt * 16 + r16;
                float v = acc[mt][nt][r];
                if (ADD_BIAS) v += bias[col];
                C[(size_t)row * N + col] = (OutT)v;
            }
}

// ---------------------------------------------------------------------------
// Flash attention. Block = 4 waves = 128 q rows (32/wave, 2 subtiles of 16).
// Computes S^T = K @ Q^T so lane owns q = lane&15 (softmax reductions = 2
// shfl_xor over quads; P written kv-contiguous as ds_write_b64).
// P -> LDS -> A-layout -> PV with V^T tiles (contiguous b128 reads).
// ---------------------------------------------------------------------------
__global__ __launch_bounds__(256) void attn_kernel(const bf16* __restrict__ qkv,
                                                   const bf16* __restrict__ vt,
                                                   bf16* __restrict__ out) {
    const int LKT = 72, LVT = 136;
    __shared__ bf16 Ks[128 * LKT];      // K tile [kv][d], padded
    __shared__ bf16 Vs[64 * LVT];       // V^T tile [d][kv], padded
    __shared__ bf16 Ps[4][16 * LVT];    // per-wave P [q][kv], padded

    int t = threadIdx.x;
    int lane = t & 63, w = t >> 6;
    int quad = lane >> 4, r16 = lane & 15;
    int bh = blockIdx.y, b = bh >> 3, h = bh & 7;
    int qw = blockIdx.x * 128 + w * 32;

    // Q fragments (B-operand of S^T): lane holds Q[q=r16][d=quad*8+j]
    bf16x8 qf[2][2];
#pragma unroll
    for (int sub = 0; sub < 2; ++sub)
#pragma unroll
        for (int kh = 0; kh < 2; ++kh)
            qf[sub][kh] = *(const bf16x8*)&qkv[(size_t)(b * 2048 + qw + sub * 16 + r16) * 1536 +
                                               h * 64 + kh * 32 + quad * 8];

    float m_i[2] = {-1e30f, -1e30f};
    float l_i[2] = {0.f, 0.f};
    const f32x4 fzero = {0.f, 0.f, 0.f, 0.f};
    f32x4 o_acc[2][4];
#pragma unroll
    for (int s = 0; s < 2; ++s)
#pragma unroll
        for (int tt = 0; tt < 4; ++tt) o_acc[s][tt] = fzero;

    int sr = t >> 3, sc = (t & 7) * 8;     // K staging
    int vr = t >> 4, vc = (t & 15) * 8;    // V staging

    for (int kv0 = 0; kv0 < 2048; kv0 += 128) {
        __syncthreads();
#pragma unroll
        for (int p = 0; p < 4; ++p) {
            int r = p * 32 + sr;
            *(bf16x8*)&Ks[r * LKT + sc] =
                *(const bf16x8*)&qkv[(size_t)(b * 2048 + kv0 + r) * 1536 + 512 + h * 64 + sc];
        }
#pragma unroll
        for (int p = 0; p < 4; ++p) {
            int r = p * 16 + vr;
            *(bf16x8*)&Vs[r * LVT + vc] =
                *(const bf16x8*)&vt[(size_t)(bh * 64 + r) * 2048 + kv0 + vc];
        }
        __syncthreads();

        // S^T = K @ Q^T : D row = kv (quad*4+reg within group g), col = q (r16)
        f32x4 sacc[2][8];
#pragma unroll
        for (int s = 0; s < 2; ++s)
#pragma unroll
            for (int g = 0; g < 8; ++g) sacc[s][g] = fzero;
#pragma unroll
        for (int g = 0; g < 8; ++g)
#pragma unroll
            for (int kh = 0; kh < 2; ++kh) {
                bf16x8 kf = *(const bf16x8*)&Ks[(g * 16 + r16) * LKT + kh * 32 + quad * 8];
                sacc[0][g] = MFMA16(kf, qf[0][kh], sacc[0][g]);
                sacc[1][g] = MFMA16(kf, qf[1][kh], sacc[1][g]);
            }

#pragma unroll
        for (int sub = 0; sub < 2; ++sub) {
            // online softmax: lane's q-row is r16 (replicated across 4 quads)
            float cm = -1e30f;
#pragma unroll
            for (int g = 0; g < 8; ++g)
#pragma unroll
                for (int r = 0; r < 4; ++r) cm = fmaxf(cm, sacc[sub][g][r]);
            cm = fmaxf(cm, __shfl_xor(cm, 16));
            cm = fmaxf(cm, __shfl_xor(cm, 32));
            cm *= 0.125f;  // scale = dh^-0.5
            float mnew = fmaxf(m_i[sub], cm);
            float alpha = __expf(m_i[sub] - mnew);
            m_i[sub] = mnew;
            float psum = 0.f;
#pragma unroll
            for (int g = 0; g < 8; ++g) {
                bf16x4 pb;
#pragma unroll
                for (int r = 0; r < 4; ++r) {
                    float p = __expf(sacc[sub][g][r] * 0.125f - mnew);
                    psum += p;
                    pb[r] = (bf16)p;
                }
                // P[q=r16][kv = g*16 + quad*4 + r] : packed 8B write
                *(bf16x4*)&Ps[w][r16 * LVT + g * 16 + quad * 4] = pb;
            }
            psum += __shfl_xor(psum, 16);
            psum += __shfl_xor(psum, 32);
            l_i[sub] = l_i[sub] * alpha + psum;

            // rescale O: O rows are q = quad*4+reg -> fetch alpha from lane q
#pragma unroll
            for (int r = 0; r < 4; ++r) {
                float a_o = __shfl(alpha, quad * 4 + r);
#pragma unroll
                for (int tt = 0; tt < 4; ++tt) o_acc[sub][tt][r] *= a_o;
            }

            // PV: A = P[q][kv] (r16 row, contiguous kv), B = V^T[d][kv]
#pragma unroll
            for (int kc = 0; kc < 4; ++kc) {
                bf16x8 pf = *(const bf16x8*)&Ps[w][r16 * LVT + kc * 32 + quad * 8];
#pragma unroll
                for (int tt = 0; tt < 4; ++tt) {
                    bf16x8 vf = *(const bf16x8*)&Vs[(tt * 16 + r16) * LVT + kc * 32 + quad * 8];
                    o_acc[sub][tt] = MFMA16(pf, vf, o_acc[sub][tt]);
                }
            }
        }
    }

    // epilogue: divide by l, write [b][n][h*64+d]
#pragma unroll
    for (int sub = 0; sub < 2; ++sub)
#pragma unroll
        for (int r = 0; r < 4; ++r) {
            float linv = 1.0f / __shfl(l_i[sub], quad * 4 + r);
            int row = b * 2048 + qw + sub * 16 + quad * 4 + r;
#pragma unroll
            for (int tt = 0; tt < 4; ++tt)
                out[(size_t)row * 512 + h * 64 + tt * 16 + r16] =
                    (bf16)(o_acc[sub][tt][r] * linv);
        }
}

// ---------------------------------------------------------------------------
extern "C" void kernel_launch(void* const* d_in, const int* in_sizes, int n_in,
                              void* d_out, int out_size, void* d_ws, size_t ws_size,
                              hipStream_t stream) {
    const float* x     = (const float*)d_in[0];   // [4*2048][512] f32
    const float* w_qkv = (const float*)d_in[1];   // [512][1536]   f32
    const float* w_out = (const float*)d_in[2];   // [512][512]    f32
    const float* b_out = (const float*)d_in[3];   // [512]         f32
    float* out = (float*)d_out;                   // [4*2048][512] f32

    char* ws = (char*)d_ws;
    size_t off = 0;
    bf16* xb    = (bf16*)(ws + off); off += (size_t)8192 * 512 * 2;        // 8 MB
    bf16* wqkvT = (bf16*)(ws + off); off += (size_t)1536 * 512 * 2;        // 1.5 MB
    bf16* woutT = (bf16*)(ws + off); off += (size_t)512 * 512 * 2;         // 0.5 MB
    bf16* qkv   = (bf16*)(ws + off); off += (size_t)8192 * 1536 * 2;       // 24 MB
    bf16* vt    = (bf16*)(ws + off); off += (size_t)32 * 64 * 2048 * 2;    // 8 MB
    bf16* attn  = (bf16*)(ws + off);                                       // 8 MB

    f32_to_bf16_kernel<<<4096, 256, 0, stream>>>(x, xb, 8192 * 512);
    transpose_f2b<<<dim3(48, 16), 256, 0, stream>>>(w_qkv, wqkvT, 512, 1536);
    transpose_f2b<<<dim3(16, 16), 256, 0, stream>>>(w_out, woutT, 512, 512);
    gemm_bt_kernel<0, bf16><<<dim3(12, 64), 256, 0, stream>>>(xb, wqkvT, nullptr, qkv,
                                                              8192, 1536, 512);
    transpose_v_kernel<<<dim3(64, 2, 32), 256, 0, stream>>>(qkv, vt);
    attn_kernel<<<dim3(16, 32), 256, 0, stream>>>(qkv, vt, attn);
    gemm_bt_kernel<1, float><<<dim3(4, 64), 256, 0, stream>>>(attn, woutT, b_out, out,
                                                              8192, 512, 512);
}